// Round 6
// baseline (1081.611 us; speedup 1.0000x reference)
//
#include <hip/hip_runtime.h>
#include <hip/hip_bf16.h>
#include <cstdint>

// PhaseEncodingSNN: B=64, T=512, I=256, H=512, O=256.
// R6 change: force W-slice register residency in the recurrent scan.
//  - R3/R4 counters showed VGPR_Count=48 for k_recurrent_cp despite
//    float Wreg[64]: the compiler's occupancy heuristic evicted the W slice,
//    re-fetching 128 KB/CU/step from L2 (the R1 disease at 1/8 scale).
//  - Fix: __launch_bounds__(512, 2) -> 2 waves/SIMD (1 block/CU), 256-VGPR
//    budget, W stays in registers. Transport stays the PROVEN agent-scope
//    sentinel exchange (R5's sc0/XCD experiment shelved: unbounded spin on
//    unverified cache semantics is a hang risk; needs a bounded-spin +
//    guaranteed-fallback design before retrying).
// GEMMs (split-bf16 MFMA), lif1, attend identical to R4.

#define T_STEPS 512
#define BATCH 64
#define HID 512
#define IN_DIM 256
#define OUT_DIM 256
#define BETA 0.9f
#define THR 1.0f
#define SENT 0x7FC00000u

typedef __attribute__((ext_vector_type(8))) short short8;
typedef __attribute__((ext_vector_type(4))) float float4v;
typedef unsigned short ushort_t;

// ---------------------------------------------------------------- NaN fill
__global__ __launch_bounds__(256) void k_fill_nan(uint32_t* __restrict__ P) {
  const int idx = blockIdx.x * 256 + threadIdx.x;  // 65536 threads
  uint4 s = make_uint4(SENT, SENT, SENT, SENT);
  uint4* p4 = (uint4*)P;
  for (int i = idx; i < (32768 * 512) / 4; i += 65536) p4[i] = s;
}

// ---------------------------------------------------------------- fp32 -> hi/lo bf16 split
__global__ __launch_bounds__(256) void k_split(const float* __restrict__ src,
                                               ushort_t* __restrict__ hi,
                                               ushort_t* __restrict__ lo, int n) {
  int i = blockIdx.x * 256 + threadIdx.x;
  const int stride = gridDim.x * 256;
  for (; i < n; i += stride) {
    float v = src[i];
    uint32_t u = __float_as_uint(v);
    uint32_t rh = u + 0x7FFFu + ((u >> 16) & 1u);   // RNE to bf16
    ushort_t h = (ushort_t)(rh >> 16);
    float hf = __uint_as_float(((uint32_t)h) << 16);
    float l = v - hf;
    uint32_t ul = __float_as_uint(l);
    uint32_t rl = ul + 0x7FFFu + ((ul >> 16) & 1u);
    hi[i] = h;
    lo[i] = (ushort_t)(rl >> 16);
  }
}

// ---------------------------------------------------------------- softmax over t
__global__ __launch_bounds__(256) void k_softmax_t(
    const float* __restrict__ TA, float* __restrict__ attn) {
  __shared__ float redm[8][32];
  __shared__ float reds[8][32];
  const int ol = threadIdx.x & 31;
  const int tg = threadIdx.x >> 5;
  const int o = blockIdx.x * 32 + ol;
  float mx = -1e30f;
  for (int i = 0; i < 64; ++i) {
    float v = TA[(size_t)(tg * 64 + i) * OUT_DIM + o];
    mx = fmaxf(mx, v);
  }
  redm[tg][ol] = mx;
  __syncthreads();
  float m = redm[0][ol];
#pragma unroll
  for (int j = 1; j < 8; ++j) m = fmaxf(m, redm[j][ol]);
  float s = 0.f;
  for (int i = 0; i < 64; ++i) {
    float v = TA[(size_t)(tg * 64 + i) * OUT_DIM + o];
    s += __expf(v - m);
  }
  reds[tg][ol] = s;
  __syncthreads();
  float tot = 0.f;
#pragma unroll
  for (int j = 0; j < 8; ++j) tot += reds[j][ol];
  const float inv = 1.0f / tot;
  for (int i = 0; i < 64; ++i) {
    int t = tg * 64 + i;
    float v = TA[(size_t)t * OUT_DIM + o];
    attn[(size_t)t * OUT_DIM + o] = __expf(v - m) * inv;
  }
}

// ---------------------------------------------------------------- MFMA GEMM, 3-term split
__global__ __launch_bounds__(256) void k_gemm_split3(
    const ushort_t* __restrict__ Ahi, const ushort_t* __restrict__ Alo,
    const ushort_t* __restrict__ Bhi, const ushort_t* __restrict__ Blo,
    const float* __restrict__ bias, float* __restrict__ C,
    int M, int N, int K) {
  __shared__ ushort_t At[2][128 * 40];
  __shared__ ushort_t Bt[2][128 * 40];
  const int tid = threadIdx.x;
  const int row0 = blockIdx.x * 128, col0 = blockIdx.y * 128;
  const int w = tid >> 6, lane = tid & 63;
  const int wm = (w >> 1) * 64, wn = (w & 1) * 64;
  const int l15 = lane & 15, quad = lane >> 4;
  float4v acc[4][4];
#pragma unroll
  for (int i = 0; i < 4; ++i)
#pragma unroll
    for (int j = 0; j < 4; ++j) acc[i][j] = (float4v){0.f, 0.f, 0.f, 0.f};

  for (int k0 = 0; k0 < K; k0 += 32) {
#pragma unroll
    for (int it = 0; it < 2; ++it) {
      int idx = it * 256 + tid;          // 0..511
      int r = idx >> 2;                  // row 0..127
      int c8 = (idx & 3) << 3;           // k-offset {0,8,16,24}
      *(uint4*)(&At[0][r * 40 + c8]) =
          *(const uint4*)(&Ahi[(size_t)(row0 + r) * K + k0 + c8]);
      *(uint4*)(&At[1][r * 40 + c8]) =
          *(const uint4*)(&Alo[(size_t)(row0 + r) * K + k0 + c8]);
      *(uint4*)(&Bt[0][r * 40 + c8]) =
          *(const uint4*)(&Bhi[(size_t)(col0 + r) * K + k0 + c8]);
      *(uint4*)(&Bt[1][r * 40 + c8]) =
          *(const uint4*)(&Blo[(size_t)(col0 + r) * K + k0 + c8]);
    }
    __syncthreads();
    short8 ah[4], al[4], bh[4], bl[4];
    const int koff = quad * 8;
#pragma unroll
    for (int i = 0; i < 4; ++i) {
      ah[i] = *(const short8*)(&At[0][(wm + i * 16 + l15) * 40 + koff]);
      al[i] = *(const short8*)(&At[1][(wm + i * 16 + l15) * 40 + koff]);
      bh[i] = *(const short8*)(&Bt[0][(wn + i * 16 + l15) * 40 + koff]);
      bl[i] = *(const short8*)(&Bt[1][(wn + i * 16 + l15) * 40 + koff]);
    }
#pragma unroll
    for (int i = 0; i < 4; ++i)
#pragma unroll
      for (int j = 0; j < 4; ++j) {
        acc[i][j] = __builtin_amdgcn_mfma_f32_16x16x32_bf16(ah[i], bh[j], acc[i][j], 0, 0, 0);
        acc[i][j] = __builtin_amdgcn_mfma_f32_16x16x32_bf16(ah[i], bl[j], acc[i][j], 0, 0, 0);
        acc[i][j] = __builtin_amdgcn_mfma_f32_16x16x32_bf16(al[i], bh[j], acc[i][j], 0, 0, 0);
      }
    __syncthreads();
  }
#pragma unroll
  for (int j = 0; j < 4; ++j) {
    const int col = col0 + wn + j * 16 + l15;
    const float bv = bias ? bias[col] : 0.f;
#pragma unroll
    for (int i = 0; i < 4; ++i) {
#pragma unroll
      for (int r = 0; r < 4; ++r) {
        int row = row0 + wm + i * 16 + quad * 4 + r;
        C[(size_t)row * N + col] = acc[i][j][r] + bv;
      }
    }
  }
}

// ---------------------------------------------------------------- MFMA GEMM, spike-A 2-term
__global__ __launch_bounds__(256) void k_gemm_spike2(
    const float* __restrict__ A, const ushort_t* __restrict__ Bhi,
    const ushort_t* __restrict__ Blo, const float* __restrict__ bias,
    float* __restrict__ C, int M, int N, int K) {
  __shared__ ushort_t At[128 * 72];
  __shared__ ushort_t Bt[2][128 * 72];
  const int tid = threadIdx.x;
  const int row0 = blockIdx.x * 128, col0 = blockIdx.y * 128;
  const int w = tid >> 6, lane = tid & 63;
  const int wm = (w >> 1) * 64, wn = (w & 1) * 64;
  const int l15 = lane & 15, quad = lane >> 4;
  float4v acc[4][4];
#pragma unroll
  for (int i = 0; i < 4; ++i)
#pragma unroll
    for (int j = 0; j < 4; ++j) acc[i][j] = (float4v){0.f, 0.f, 0.f, 0.f};

  for (int k0 = 0; k0 < K; k0 += 64) {
#pragma unroll
    for (int it = 0; it < 4; ++it) {
      int idx = it * 256 + tid;          // 0..1023
      int r = idx >> 3;                  // row 0..127
      int c8 = (idx & 7) << 3;           // k-offset 0..56 step 8
      uint4 pa = *(const uint4*)(&A[(size_t)(row0 + r) * K + k0 + c8]);
      uint4 pb = *(const uint4*)(&A[(size_t)(row0 + r) * K + k0 + c8 + 4]);
      uint4 st;
      st.x = (pa.x >> 16) | (pa.y & 0xFFFF0000u);
      st.y = (pa.z >> 16) | (pa.w & 0xFFFF0000u);
      st.z = (pb.x >> 16) | (pb.y & 0xFFFF0000u);
      st.w = (pb.z >> 16) | (pb.w & 0xFFFF0000u);
      *(uint4*)(&At[r * 72 + c8]) = st;
      *(uint4*)(&Bt[0][r * 72 + c8]) =
          *(const uint4*)(&Bhi[(size_t)(col0 + r) * K + k0 + c8]);
      *(uint4*)(&Bt[1][r * 72 + c8]) =
          *(const uint4*)(&Blo[(size_t)(col0 + r) * K + k0 + c8]);
    }
    __syncthreads();
#pragma unroll
    for (int ks = 0; ks < 2; ++ks) {
      short8 a[4], bh[4], bl[4];
      const int koff = ks * 32 + quad * 8;
#pragma unroll
      for (int i = 0; i < 4; ++i) {
        a[i] = *(const short8*)(&At[(wm + i * 16 + l15) * 72 + koff]);
        bh[i] = *(const short8*)(&Bt[0][(wn + i * 16 + l15) * 72 + koff]);
        bl[i] = *(const short8*)(&Bt[1][(wn + i * 16 + l15) * 72 + koff]);
      }
#pragma unroll
      for (int i = 0; i < 4; ++i)
#pragma unroll
        for (int j = 0; j < 4; ++j) {
          acc[i][j] = __builtin_amdgcn_mfma_f32_16x16x32_bf16(a[i], bh[j], acc[i][j], 0, 0, 0);
          acc[i][j] = __builtin_amdgcn_mfma_f32_16x16x32_bf16(a[i], bl[j], acc[i][j], 0, 0, 0);
        }
    }
    __syncthreads();
  }
#pragma unroll
  for (int j = 0; j < 4; ++j) {
    const int col = col0 + wn + j * 16 + l15;
    const float bv = bias ? bias[col] : 0.f;
#pragma unroll
    for (int i = 0; i < 4; ++i) {
#pragma unroll
      for (int r = 0; r < 4; ++r) {
        int row = row0 + wm + i * 16 + quad * 4 + r;
        C[(size_t)row * N + col] = acc[i][j][r] + bv;
      }
    }
  }
}

// ---------------------------------------------------------------- LIF scan #1
__global__ __launch_bounds__(256) void k_lif1(float* __restrict__ p) {
  const int id = blockIdx.x * 256 + threadIdx.x;  // 0..32767
  const size_t base = (size_t)(id >> 9) * (T_STEPS * HID) + (id & 511);
  float mem = 0.f;
  for (int t0 = 0; t0 < T_STEPS; t0 += 8) {
    float v[8];
#pragma unroll
    for (int j = 0; j < 8; ++j) v[j] = p[base + (size_t)(t0 + j) * HID];
#pragma unroll
    for (int j = 0; j < 8; ++j) {
      float nm = BETA * mem + v[j];
      float sp = nm > THR ? 1.0f : 0.0f;
      p[base + (size_t)(t0 + j) * HID] = sp;
      mem = nm - sp;
    }
  }
}

// ---------------------------------------------------------------- recurrent scan
// R3 structure, but __launch_bounds__(512, 2): 256-VGPR budget so the
// 64-value W slice is register-resident (VGPR_Count must rise above ~96;
// at 48 the compiler was re-streaming W from L2 every step).
__global__ __launch_bounds__(512, 2) void k_recurrent_cp(
    const float* __restrict__ W, const float* __restrict__ b_hh,
    float* __restrict__ rp, float* __restrict__ P) {
  const int tid = threadIdx.x;
  const int grp = blockIdx.x >> 3;
  const int j = blockIdx.x & 7;
  const int seg = tid >> 6;
  const int gl = tid & 63;
  const int g0 = j << 6;

  __shared__ float memLDS[2][HID];
  __shared__ float scratch[8][2][64];

  for (int i = tid; i < 2 * HID; i += 512) ((float*)memLDS)[i] = 0.f;

  float Wreg[64];
  {
    const float* wrow = W + (size_t)(g0 + gl) * HID + (seg << 6);
#pragma unroll
    for (int k4 = 0; k4 < 16; ++k4) {
      float4 w4 = *(const float4*)(wrow + 4 * k4);
      Wreg[4 * k4 + 0] = w4.x; Wreg[4 * k4 + 1] = w4.y;
      Wreg[4 * k4 + 2] = w4.z; Wreg[4 * k4 + 3] = w4.w;
    }
  }

  const int ob = tid >> 6;
  const int ogl = tid & 63;
  const int og = g0 + ogl;
  const size_t rp_base = (size_t)(grp * 2 + ob) * (T_STEPS * HID) + og;
  float bhh_v = 0.f;
  if (tid < 128) bhh_v = b_hh[og];

  const int rg = (tid < g0) ? tid : tid + 64;

  const uint32_t* Pu = (const uint32_t*)P;
  float* Pf = P;

  __syncthreads();

  for (int t = 0; t < T_STEPS; ++t) {
    float ip_v = 0.f;
    if (tid < 128) ip_v = rp[rp_base + (size_t)t * HID];

    if (t > 0 && tid < 448) {
      const size_t slot = ((size_t)(t - 1) * 32 + grp) * 1024;
      uint32_t u0 = __hip_atomic_load(Pu + slot + rg, __ATOMIC_RELAXED,
                                      __HIP_MEMORY_SCOPE_AGENT);
      uint32_t u1 = __hip_atomic_load(Pu + slot + 512 + rg, __ATOMIC_RELAXED,
                                      __HIP_MEMORY_SCOPE_AGENT);
      while (u0 == SENT || u1 == SENT) {
        __builtin_amdgcn_s_sleep(1);
        if (u0 == SENT)
          u0 = __hip_atomic_load(Pu + slot + rg, __ATOMIC_RELAXED,
                                 __HIP_MEMORY_SCOPE_AGENT);
        if (u1 == SENT)
          u1 = __hip_atomic_load(Pu + slot + 512 + rg, __ATOMIC_RELAXED,
                                 __HIP_MEMORY_SCOPE_AGENT);
      }
      memLDS[0][rg] = __uint_as_float(u0);
      memLDS[1][rg] = __uint_as_float(u1);
    }
    __syncthreads();

    float p0a = 0.f, p0b = 0.f, p1a = 0.f, p1b = 0.f;
    {
      const float4* m0 = (const float4*)&memLDS[0][seg << 6];
      const float4* m1 = (const float4*)&memLDS[1][seg << 6];
#pragma unroll
      for (int k4 = 0; k4 < 16; ++k4) {
        float4 a = m0[k4];
        float4 b = m1[k4];
        p0a = fmaf(Wreg[4 * k4 + 0], a.x, p0a);
        p0b = fmaf(Wreg[4 * k4 + 1], a.y, p0b);
        p0a = fmaf(Wreg[4 * k4 + 2], a.z, p0a);
        p0b = fmaf(Wreg[4 * k4 + 3], a.w, p0b);
        p1a = fmaf(Wreg[4 * k4 + 0], b.x, p1a);
        p1b = fmaf(Wreg[4 * k4 + 1], b.y, p1b);
        p1a = fmaf(Wreg[4 * k4 + 2], b.z, p1a);
        p1b = fmaf(Wreg[4 * k4 + 3], b.w, p1b);
      }
    }
    scratch[seg][0][gl] = p0a + p0b;
    scratch[seg][1][gl] = p1a + p1b;
    __syncthreads();

    if (tid < 128) {
      float s = 0.f;
#pragma unroll
      for (int ss = 0; ss < 8; ++ss) s += scratch[ss][ob][ogl];
      const float m_old = memLDS[ob][og];
      const float nm = BETA * m_old + ip_v + s + bhh_v;
      const float sp = nm > THR ? 1.0f : 0.0f;
      rp[rp_base + (size_t)t * HID] = sp;
      const float mnew = nm - sp;
      memLDS[ob][og] = mnew;
      const size_t slot = ((size_t)t * 32 + grp) * 1024;
      __hip_atomic_store(Pf + slot + (size_t)ob * 512 + og, mnew,
                         __ATOMIC_RELAXED, __HIP_MEMORY_SCOPE_AGENT);
    }
  }
}

// ---------------------------------------------------------------- attend + threshold
__global__ __launch_bounds__(256) void k_attend(
    const float* __restrict__ op, const float* __restrict__ attn,
    const float* __restrict__ b_out, float* __restrict__ out) {
  const int b = blockIdx.x;
  const int o = threadIdx.x;
  float s = b_out[o];
  const float* opb = op + (size_t)b * T_STEPS * OUT_DIM + o;
  for (int t0 = 0; t0 < T_STEPS; t0 += 8) {
    float av[8], pv[8];
#pragma unroll
    for (int j = 0; j < 8; ++j) {
      av[j] = attn[(size_t)(t0 + j) * OUT_DIM + o];
      pv[j] = opb[(size_t)(t0 + j) * OUT_DIM];
    }
#pragma unroll
    for (int j = 0; j < 8; ++j) s = fmaf(av[j], pv[j], s);
  }
  out[b * OUT_DIM + o] = s > THR ? 1.0f : 0.0f;
}

// ---------------------------------------------------------------- launch
extern "C" void kernel_launch(void* const* d_in, const int* in_sizes, int n_in,
                              void* d_out, int out_size, void* d_ws, size_t ws_size,
                              hipStream_t stream) {
  (void)in_sizes; (void)n_in; (void)out_size; (void)ws_size;
  const float* x     = (const float*)d_in[0];
  const float* W_in  = (const float*)d_in[1];
  const float* b_in  = (const float*)d_in[2];
  const float* W_ih  = (const float*)d_in[3];
  const float* b_ih  = (const float*)d_in[4];
  const float* W_hh  = (const float*)d_in[5];
  const float* b_hh  = (const float*)d_in[6];
  const float* W_out = (const float*)d_in[7];
  const float* b_out = (const float*)d_in[8];
  const float* TA    = (const float*)d_in[9];

  float* ws = (float*)d_ws;
  float* proj  = ws;                           // 16.78M floats: GEMM1 out / P / out_proj
  float* rproj = proj + (size_t)32768 * 512;   // 16.78M floats: x-splits, then GEMM2 out
  float* attn  = rproj + (size_t)32768 * 512;  // 131072 floats
  ushort_t* wih_hi = (ushort_t*)(attn + 512 * 256);
  ushort_t* wih_lo = wih_hi + 512 * 512;
  ushort_t* win_hi = wih_lo + 512 * 512;
  ushort_t* win_lo = win_hi + 512 * 256;
  ushort_t* wout_hi = win_lo + 512 * 256;
  ushort_t* wout_lo = wout_hi + 256 * 512;
  ushort_t* x_hi = (ushort_t*)rproj;
  ushort_t* x_lo = x_hi + (size_t)32768 * 256;
  float* P = proj;            // exchange slots [t][grp][b][g]
  float* out_proj = proj;     // (b*T, O) fp32, written after recurrent

  k_softmax_t<<<8, 256, 0, stream>>>(TA, attn);
  k_split<<<4096, 256, 0, stream>>>(x, x_hi, x_lo, 32768 * 256);
  k_split<<<512, 256, 0, stream>>>(W_in, win_hi, win_lo, 512 * 256);
  k_split<<<512, 256, 0, stream>>>(W_ih, wih_hi, wih_lo, 512 * 512);
  k_split<<<512, 256, 0, stream>>>(W_out, wout_hi, wout_lo, 256 * 512);

  // GEMM1: proj = x @ W_in^T + b_in   (M=32768, N=512, K=256)
  k_gemm_split3<<<dim3(256, 4), 256, 0, stream>>>(
      x_hi, x_lo, win_hi, win_lo, b_in, proj, 32768, 512, 256);
  k_lif1<<<128, 256, 0, stream>>>(proj);
  // GEMM2: rproj = spikes @ W_ih^T + b_ih   (M=32768, N=512, K=512)
  k_gemm_spike2<<<dim3(256, 4), 256, 0, stream>>>(
      proj, wih_hi, wih_lo, b_ih, rproj, 32768, 512, 512);
  k_fill_nan<<<256, 256, 0, stream>>>((uint32_t*)P);  // proj dead after GEMM2
  k_recurrent_cp<<<256, 512, 0, stream>>>(W_hh, b_hh, rproj, P);
  // GEMM3: out_proj = tspikes @ W_out^T   (M=32768, N=256, K=512, no bias)
  k_gemm_spike2<<<dim3(256, 2), 256, 0, stream>>>(
      rproj, wout_hi, wout_lo, nullptr, out_proj, 32768, 256, 512);
  k_attend<<<64, 256, 0, stream>>>(out_proj, attn, b_out, (float*)d_out);
}